// Round 1
// baseline (394.809 us; speedup 1.0000x reference)
//
#include <hip/hip_runtime.h>

// LIF bitshift-decay scan: B=32, T=1024, N=1024, n_syn=2.
// One thread per (b, n) scan; 512 blocks x 64 threads = 32768 threads = 2 waves/CU.
//
// v2: 4-slot rolling register pipeline at prefetch distance 3 (UU=8 steps/chunk,
// 16 loads/chunk, 48 loads continuously in flight per wave -> counted vmcnt(48)
// waits instead of the old 2-buffer copy's per-chunk vmcnt(0) drain).
//
// Numerics: must be bit-exact vs numpy fp32 reference (spike threshold is a hard
// discontinuity). All decay factors are powers of two (exact multiplies), and the
// add order below matches the reference exactly:
//   isyn = (isyn - isyn*sd) + x
//   vmem = (vmem - vmem*md) + (i0 + i1)

#define TT 1024
#define NN 1024
#define BB 32
#define UU 8            // time-steps per chunk
#define NCHUNK (TT / UU) // 128 chunks

// Load chunk c (UU steps, both synapses) into register arrays X0/X1.
#define LOADC(X0, X1, c) do {                                          \
    const float* __restrict__ p_ = ip + (size_t)(c) * (UU * 2048);     \
    _Pragma("unroll")                                                  \
    for (int j_ = 0; j_ < UU; ++j_) {                                  \
        X0[j_] = p_[j_ * 2048];                                        \
        X1[j_] = p_[j_ * 2048 + 1024];                                 \
    }                                                                  \
} while (0)

// Compute+store chunk c from register arrays X0/X1 (exact ref add order).
#define COMPC(X0, X1, c) do {                                          \
    float* __restrict__ po_ = op + (size_t)(c) * (UU * NN);            \
    _Pragma("unroll")                                                  \
    for (int j_ = 0; j_ < UU; ++j_) {                                  \
        i0 = (i0 - i0 * SD0) + X0[j_];                                 \
        i1 = (i1 - i1 * SD1) + X1[j_];                                 \
        float vd_ = v - v * MD;                                        \
        v = vd_ + (i0 + i1);                                           \
        float spk_ = (v >= 1.0f) ? 1.0f : 0.0f;                        \
        v -= spk_;              /* membrane-subtract reset (thr=1.0) */ \
        po_[j_ * NN] = spk_;                                           \
    }                                                                  \
} while (0)

__global__ __launch_bounds__(64, 1)
void lif_scan_kernel(const float* __restrict__ in, float* __restrict__ out) {
    const int gid = blockIdx.x * 64 + threadIdx.x;   // 0 .. 32767
    const int b = gid >> 10;                          // / NN
    const int n = gid & (NN - 1);

    // input layout:  ((b*T + t)*2 + s)*N + n  -> ip + t*2048 + s*1024
    const float* __restrict__ ip = in + (size_t)b * TT * 2 * NN + n;
    // output layout: (b*T + t)*N + n          -> op + t*1024
    float* __restrict__ op = out + (size_t)b * TT * NN + n;

    const float SD0 = 0.25f;   // 2^-2  (tau_syn=5 -> dash 2)
    const float SD1 = 0.5f;    // 2^-1  (tau_syn=2 -> dash 1)
    const float MD  = 0.125f;  // 2^-3  (tau_mem=10 -> dash 3)

    float i0 = 0.0f, i1 = 0.0f, v = 0.0f;

    // 4 rotating chunk buffers (statically named -> no register copies,
    // all indexing compile-time constant -> stays in VGPRs).
    float a0[UU], a1[UU];
    float b0[UU], b1[UU];
    float c0[UU], c1[UU];
    float d0[UU], d1[UU];

    // Prologue: fill the pipeline 3 chunks deep.
    LOADC(a0, a1, 0);
    LOADC(b0, b1, 1);
    LOADC(c0, c1, 2);

    // Main loop: compute chunk c while chunks c+1..c+3 are in flight.
    // 31 iterations x 4 chunks = chunks 0..123 computed, loads up to 126.
    int c = 0;
    for (int i = 0; i < (NCHUNK / 4) - 1; ++i, c += 4) {
        LOADC(d0, d1, c + 3);  COMPC(a0, a1, c);
        LOADC(a0, a1, c + 4);  COMPC(b0, b1, c + 1);
        LOADC(b0, b1, c + 5);  COMPC(c0, c1, c + 2);
        LOADC(c0, c1, c + 6);  COMPC(d0, d1, c + 3);
    }

    // Epilogue: c == 124 here; slots hold A=124, B=125, C=126.
    LOADC(d0, d1, NCHUNK - 1);          // chunk 127
    COMPC(a0, a1, NCHUNK - 4);
    COMPC(b0, b1, NCHUNK - 3);
    COMPC(c0, c1, NCHUNK - 2);
    COMPC(d0, d1, NCHUNK - 1);
}

extern "C" void kernel_launch(void* const* d_in, const int* in_sizes, int n_in,
                              void* d_out, int out_size, void* d_ws, size_t ws_size,
                              hipStream_t stream) {
    const float* in = (const float*)d_in[0];
    float* out = (float*)d_out;
    dim3 grid(BB * NN / 64);   // 512 blocks -> ~2 blocks/CU on 256 CUs
    dim3 block(64);            // one wave per block
    hipLaunchKernelGGL(lif_scan_kernel, grid, block, 0, stream, in, out);
}